// Round 1
// baseline (302.220 us; speedup 1.0000x reference)
//
#include <hip/hip_runtime.h>

static constexpr int CH = 128;   // CHANNELS (fixed by reference)

// ---------------------------------------------------------------------------
// Detect whether edge_index arrived as int64 (JAX x64 on) or int32 (x64 off).
// int64 little-endian: high word of each element is 0 (indices in [0, 50000)).
// Check the first 128 elements' high words; all-zero => int64.
// ---------------------------------------------------------------------------
__global__ void detect_idx64(const unsigned int* __restrict__ idxw,
                             int* __restrict__ flag) {
    const int t = threadIdx.x;
    unsigned int nz = 0;
    for (int i = t; i < 128; i += 64) nz |= idxw[2 * i + 1];
    unsigned long long b = __ballot(nz != 0u);
    if (t == 0) flag[0] = (b == 0ULL) ? 1 : 0;
}

// ---------------------------------------------------------------------------
// Node precompute:
//   P[n][c] = sum_k tok[n][k]*w1[k][c]       - (cx*w1[256][c] + cy*w1[257][c])
//   Q[n][c] = sum_k tok[n][k]*w1[128+k][c]   + (cx*w1[256][c] + cy*w1[257][c]) + b1[c]
// Block = 256 threads = 8 nodes x 32 lanes; each lane owns 4 channels (float4).
// w1 (132 KB) is read by every block -> L1/L2 broadcast.
// ---------------------------------------------------------------------------
__global__ __launch_bounds__(256) void node_pre(
    const float* __restrict__ tokens, const float* __restrict__ coords,
    const float* __restrict__ w1, const float* __restrict__ b1,
    float* __restrict__ P, float* __restrict__ Q, int N) {
    __shared__ float tok[8][CH];
    const int t = threadIdx.x;
    const int g = t >> 5;        // node within block
    const int l = t & 31;        // lane -> channels 4l..4l+3
    const int n = blockIdx.x * 8 + g;

    if (n < N) {
        *(float4*)&tok[g][4 * l] =
            *(const float4*)&tokens[(size_t)n * CH + 4 * l];
    }
    __syncthreads();
    if (n >= N) return;

    float4 aP = {0.f, 0.f, 0.f, 0.f};
    float4 aQ = {0.f, 0.f, 0.f, 0.f};
    const float* __restrict__ wa = &w1[4 * l];            // rows 0..127
    const float* __restrict__ wb = &w1[CH * CH + 4 * l];  // rows 128..255
#pragma unroll 4
    for (int k = 0; k < CH; ++k) {
        const float tk = tok[g][k];
        const float4 va = *(const float4*)&wa[k * CH];
        const float4 vb = *(const float4*)&wb[k * CH];
        aP.x = fmaf(tk, va.x, aP.x);
        aP.y = fmaf(tk, va.y, aP.y);
        aP.z = fmaf(tk, va.z, aP.z);
        aP.w = fmaf(tk, va.w, aP.w);
        aQ.x = fmaf(tk, vb.x, aQ.x);
        aQ.y = fmaf(tk, vb.y, aQ.y);
        aQ.z = fmaf(tk, vb.z, aQ.z);
        aQ.w = fmaf(tk, vb.w, aQ.w);
    }

    const float cx = coords[2 * n];
    const float cy = coords[2 * n + 1];
    const float4 wc0 = *(const float4*)&w1[2 * CH * CH + 4 * l];        // row 256
    const float4 wc1 = *(const float4*)&w1[(2 * CH + 1) * CH + 4 * l];  // row 257
    const float4 bb  = *(const float4*)&b1[4 * l];

    float4 cc;
    cc.x = fmaf(cy, wc1.x, cx * wc0.x);
    cc.y = fmaf(cy, wc1.y, cx * wc0.y);
    cc.z = fmaf(cy, wc1.z, cx * wc0.z);
    cc.w = fmaf(cy, wc1.w, cx * wc0.w);

    float4 pv, qv;
    pv.x = aP.x - cc.x; pv.y = aP.y - cc.y; pv.z = aP.z - cc.z; pv.w = aP.w - cc.w;
    qv.x = aQ.x + cc.x + bb.x; qv.y = aQ.y + cc.y + bb.y;
    qv.z = aQ.z + cc.z + bb.z; qv.w = aQ.w + cc.w + bb.w;

    *(float4*)&P[(size_t)n * CH + 4 * l] = pv;
    *(float4*)&Q[(size_t)n * CH + 4 * l] = qv;
}

// ---------------------------------------------------------------------------
// Edge kernel: each 32-lane half-wave owns one edge.
//   out[e] = dot(relu(P[src] + Q[dst]), w2) + b2
// P/Q rows: 512 B contiguous -> coalesced float4 loads; 51 MB total -> L3-hot.
// ---------------------------------------------------------------------------
__global__ __launch_bounds__(256) void edge_kernel(
    const unsigned int* __restrict__ idxw, const float* __restrict__ P,
    const float* __restrict__ Q, const float* __restrict__ w2,
    const float* __restrict__ b2, float* __restrict__ out, long long E,
    const int* __restrict__ flag) {
    const int is64 = flag[0];  // uniform branch
    const int t = threadIdx.x;
    const int l = t & 31;
    const long long hw0  = (long long)blockIdx.x * (blockDim.x >> 5) + (t >> 5);
    const long long nhws = (long long)gridDim.x * (blockDim.x >> 5);
    const float4 w2v = *(const float4*)&w2[4 * l];
    const float bias = b2[0];

    for (long long e = hw0; e < E; e += nhws) {
        long long s, d;
        if (is64) {
            s = (long long)idxw[2 * e];
            d = (long long)idxw[2 * (E + e)];
        } else {
            s = (long long)idxw[e];
            d = (long long)idxw[E + e];
        }
        const float4 p = *(const float4*)&P[s * CH + 4 * l];
        const float4 q = *(const float4*)&Q[d * CH + 4 * l];
        const float hx = fmaxf(p.x + q.x, 0.f);
        const float hy = fmaxf(p.y + q.y, 0.f);
        const float hz = fmaxf(p.z + q.z, 0.f);
        const float hww = fmaxf(p.w + q.w, 0.f);
        float part = hx * w2v.x + hy * w2v.y + hz * w2v.z + hww * w2v.w;
        // reduce within the 32-lane half (xor masks < 32 stay inside the half)
        part += __shfl_xor(part, 1);
        part += __shfl_xor(part, 2);
        part += __shfl_xor(part, 4);
        part += __shfl_xor(part, 8);
        part += __shfl_xor(part, 16);
        if (l == 0) out[e] = part + bias;
    }
}

extern "C" void kernel_launch(void* const* d_in, const int* in_sizes, int n_in,
                              void* d_out, int out_size, void* d_ws,
                              size_t ws_size, hipStream_t stream) {
    const float* tokens = (const float*)d_in[0];
    const float* coords = (const float*)d_in[1];
    const unsigned int* idxw = (const unsigned int*)d_in[2];  // int32 or int64 words
    const float* w1 = (const float*)d_in[3];
    const float* b1 = (const float*)d_in[4];
    const float* w2 = (const float*)d_in[5];
    const float* b2 = (const float*)d_in[6];
    float* out = (float*)d_out;

    const int N = in_sizes[0] / CH;          // 50000
    const long long E = in_sizes[2] / 2;     // 800000

    float* Pbuf = (float*)d_ws;
    float* Qbuf = Pbuf + (size_t)N * CH;
    int* flag = (int*)(Qbuf + (size_t)N * CH);

    detect_idx64<<<1, 64, 0, stream>>>(idxw, flag);

    const int nblk_node = (N + 7) / 8;
    node_pre<<<nblk_node, 256, 0, stream>>>(tokens, coords, w1, b1, Pbuf, Qbuf, N);

    edge_kernel<<<4096, 256, 0, stream>>>(idxw, Pbuf, Qbuf, w2, b2, out, E, flag);
}

// Round 2
// 128.167 us; speedup vs baseline: 2.3580x; 2.3580x over previous
//
#include <hip/hip_runtime.h>
#include <hip/hip_bf16.h>

static constexpr int CH   = 128;   // CHANNELS
static constexpr int NCOL = 256;   // P(128) | Q(128) output columns
static constexpr int MBLK = 64;    // nodes per block
static constexpr int BK   = 16;    // K tile

// ---------------------------------------------------------------------------
// Detect whether edge_index arrived as int64 (JAX x64 on) or int32 (x64 off).
// int64 little-endian: high word of each element is 0 (indices < 50000).
// ---------------------------------------------------------------------------
__global__ void detect_idx64(const unsigned int* __restrict__ idxw,
                             int* __restrict__ flag) {
    const int t = threadIdx.x;
    unsigned int nz = 0;
    for (int i = t; i < 128; i += 64) nz |= idxw[2 * i + 1];
    unsigned long long b = __ballot(nz != 0u);
    if (t == 0) flag[0] = (b == 0ULL) ? 1 : 0;
}

__device__ inline unsigned short f2bf(float x) {
    unsigned int u = __float_as_uint(x);
    unsigned int r = (u + 0x7fffu + ((u >> 16) & 1u)) >> 16;  // RNE
    return (unsigned short)r;
}

// ---------------------------------------------------------------------------
// Node precompute as an LDS-tiled fp32 GEMM.
//   C[n][j] = sum_k tok[n][k] * B[k][j],   j<128: B=w1[k][j] (P cols)
//                                          j>=128: B=w1[128+k][j-128] (Q cols)
// Epilogue adds the coord term (-cc for P, +cc+b1 for Q) and stores bf16.
// Block: 256 thr, 64 nodes x 256 cols; per-thread 8 nodes x (4 P + 4 Q cols).
// ---------------------------------------------------------------------------
__global__ __launch_bounds__(256) void node_pre2(
    const float* __restrict__ tokens, const float* __restrict__ coords,
    const float* __restrict__ w1, const float* __restrict__ b1,
    unsigned short* __restrict__ Pb, unsigned short* __restrict__ Qb, int N) {
    __shared__ float Bt[BK][NCOL];      // 16 KB
    __shared__ float Tt[BK][MBLK + 4];  // padded stride 68 (272B, 16B-aligned)

    const int t  = threadIdx.x;
    const int n0 = blockIdx.x * MBLK;
    const int r0 = (t >> 5) * 8;   // node sub-block 0..56
    const int c0 = (t & 31) * 4;   // column group within 128

    float acc[8][8];
#pragma unroll
    for (int i = 0; i < 8; ++i)
#pragma unroll
        for (int j = 0; j < 8; ++j) acc[i][j] = 0.f;

    const int sn = t >> 2;        // staging: node 0..63
    const int sk = (t & 3) * 4;   // staging: k sub-offset 0,4,8,12

    for (int k0 = 0; k0 < CH; k0 += BK) {
        __syncthreads();  // protect previous tile's reads
        // --- stage B tile: rows k0..k0+15 of both w1 halves (1024 float4) ---
#pragma unroll
        for (int p = 0; p < 4; ++p) {
            const int f     = t + p * 256;      // 0..1023
            const int chunk = f >> 9;           // 0: P cols, 1: Q cols
            const int fi    = f & 511;
            const int row   = fi >> 5;          // 0..15
            const int cg    = (fi & 31) * 4;    // 0..124
            const int grow  = chunk ? (CH + k0 + row) : (k0 + row);
            const float4 v  = *(const float4*)&w1[(size_t)grow * CH + cg];
            *(float4*)&Bt[row][chunk * CH + cg] = v;
        }
        // --- stage token tile transposed: Tt[k][node] ---
        {
            const int nn = n0 + sn;
            float4 tv = make_float4(0.f, 0.f, 0.f, 0.f);
            if (nn < N) tv = *(const float4*)&tokens[(size_t)nn * CH + k0 + sk];
            Tt[sk + 0][sn] = tv.x;
            Tt[sk + 1][sn] = tv.y;
            Tt[sk + 2][sn] = tv.z;
            Tt[sk + 3][sn] = tv.w;
        }
        __syncthreads();
        // --- compute ---
#pragma unroll
        for (int k = 0; k < BK; ++k) {
            float a[8], b[8];
            *(float4*)&a[0] = *(const float4*)&Tt[k][r0];
            *(float4*)&a[4] = *(const float4*)&Tt[k][r0 + 4];
            *(float4*)&b[0] = *(const float4*)&Bt[k][c0];
            *(float4*)&b[4] = *(const float4*)&Bt[k][CH + c0];
#pragma unroll
            for (int i = 0; i < 8; ++i)
#pragma unroll
                for (int j = 0; j < 8; ++j)
                    acc[i][j] = fmaf(a[i], b[j], acc[i][j]);
        }
    }

    // --- epilogue: coord terms + bias, convert to bf16, store ---
    const float4 wc0 = *(const float4*)&w1[(size_t)(2 * CH) * CH + c0];      // row 256
    const float4 wc1 = *(const float4*)&w1[(size_t)(2 * CH + 1) * CH + c0];  // row 257
    const float4 bb  = *(const float4*)&b1[c0];

#pragma unroll
    for (int i = 0; i < 8; ++i) {
        const int n = n0 + r0 + i;
        if (n < N) {
            const float cx = coords[2 * n];
            const float cy = coords[2 * n + 1];
            float cc[4];
            cc[0] = fmaf(cy, wc1.x, cx * wc0.x);
            cc[1] = fmaf(cy, wc1.y, cx * wc0.y);
            cc[2] = fmaf(cy, wc1.z, cx * wc0.z);
            cc[3] = fmaf(cy, wc1.w, cx * wc0.w);
            ushort4 ps, qs;
            ps.x = f2bf(acc[i][0] - cc[0]);
            ps.y = f2bf(acc[i][1] - cc[1]);
            ps.z = f2bf(acc[i][2] - cc[2]);
            ps.w = f2bf(acc[i][3] - cc[3]);
            qs.x = f2bf(acc[i][4] + cc[0] + bb.x);
            qs.y = f2bf(acc[i][5] + cc[1] + bb.y);
            qs.z = f2bf(acc[i][6] + cc[2] + bb.z);
            qs.w = f2bf(acc[i][7] + cc[3] + bb.w);
            *(ushort4*)&Pb[(size_t)n * CH + c0] = ps;
            *(ushort4*)&Qb[(size_t)n * CH + c0] = qs;
        }
    }
}

// ---------------------------------------------------------------------------
// Edge kernel: each 32-lane half-wave owns one edge.
//   out[e] = dot(relu(P[src] + Q[dst]), w2) + b2
// P/Q rows are bf16: 256 B contiguous -> one uint2 (8B) per lane, coalesced.
// ---------------------------------------------------------------------------
__global__ __launch_bounds__(256) void edge_kernel2(
    const unsigned int* __restrict__ idxw, const unsigned short* __restrict__ Pb,
    const unsigned short* __restrict__ Qb, const float* __restrict__ w2,
    const float* __restrict__ b2, float* __restrict__ out, long long E,
    const int* __restrict__ flag) {
    const int is64 = flag[0];  // uniform branch
    const int t = threadIdx.x;
    const int l = t & 31;
    const long long hw0  = (long long)blockIdx.x * (blockDim.x >> 5) + (t >> 5);
    const long long nhws = (long long)gridDim.x * (blockDim.x >> 5);
    const float4 w2v = *(const float4*)&w2[4 * l];
    const float bias = b2[0];

    for (long long e = hw0; e < E; e += nhws) {
        long long s, d;
        if (is64) {
            s = (long long)idxw[2 * e];
            d = (long long)idxw[2 * (E + e)];
        } else {
            s = (long long)idxw[e];
            d = (long long)idxw[E + e];
        }
        const uint2 pv = *(const uint2*)&Pb[s * CH + 4 * l];
        const uint2 qv = *(const uint2*)&Qb[d * CH + 4 * l];
        const float p0 = __uint_as_float(pv.x << 16);
        const float p1 = __uint_as_float(pv.x & 0xffff0000u);
        const float p2 = __uint_as_float(pv.y << 16);
        const float p3 = __uint_as_float(pv.y & 0xffff0000u);
        const float q0 = __uint_as_float(qv.x << 16);
        const float q1 = __uint_as_float(qv.x & 0xffff0000u);
        const float q2 = __uint_as_float(qv.y << 16);
        const float q3 = __uint_as_float(qv.y & 0xffff0000u);
        const float h0 = fmaxf(p0 + q0, 0.f);
        const float h1 = fmaxf(p1 + q1, 0.f);
        const float h2 = fmaxf(p2 + q2, 0.f);
        const float h3 = fmaxf(p3 + q3, 0.f);
        float part = h0 * w2v.x + h1 * w2v.y + h2 * w2v.z + h3 * w2v.w;
        part += __shfl_xor(part, 1);
        part += __shfl_xor(part, 2);
        part += __shfl_xor(part, 4);
        part += __shfl_xor(part, 8);
        part += __shfl_xor(part, 16);
        if (l == 0) out[e] = part + bias;
    }
}

extern "C" void kernel_launch(void* const* d_in, const int* in_sizes, int n_in,
                              void* d_out, int out_size, void* d_ws,
                              size_t ws_size, hipStream_t stream) {
    const float* tokens = (const float*)d_in[0];
    const float* coords = (const float*)d_in[1];
    const unsigned int* idxw = (const unsigned int*)d_in[2];  // int32 or int64 words
    const float* w1 = (const float*)d_in[3];
    const float* b1 = (const float*)d_in[4];
    const float* w2 = (const float*)d_in[5];
    const float* b2 = (const float*)d_in[6];
    float* out = (float*)d_out;

    const int N = in_sizes[0] / CH;       // 50000
    const long long E = in_sizes[2] / 2;  // 800000

    unsigned short* Pb = (unsigned short*)d_ws;
    unsigned short* Qb = Pb + (size_t)N * CH;
    int* flag = (int*)(Qb + (size_t)N * CH);

    detect_idx64<<<1, 64, 0, stream>>>(idxw, flag);

    const int nblk_node = (N + MBLK - 1) / MBLK;
    node_pre2<<<nblk_node, 256, 0, stream>>>(tokens, coords, w1, b1, Pb, Qb, N);

    edge_kernel2<<<4096, 256, 0, stream>>>(idxw, Pb, Qb, w2, b2, out, E, flag);
}

// Round 3
// 125.923 us; speedup vs baseline: 2.4000x; 1.0178x over previous
//
#include <hip/hip_runtime.h>
#include <hip/hip_bf16.h>

static constexpr int CH   = 128;   // CHANNELS
static constexpr int NCOL = 256;   // P(128) | Q(128) output columns
static constexpr int MBLK = 64;    // nodes per block
static constexpr int BK   = 16;    // K tile

// ---------------------------------------------------------------------------
// Detect whether edge_index arrived as int64 (JAX x64 on) or int32 (x64 off).
// int64 little-endian: high word of each element is 0 (indices < 50000).
// ---------------------------------------------------------------------------
__global__ void detect_idx64(const unsigned int* __restrict__ idxw,
                             int* __restrict__ flag) {
    const int t = threadIdx.x;
    unsigned int nz = 0;
    for (int i = t; i < 128; i += 64) nz |= idxw[2 * i + 1];
    unsigned long long b = __ballot(nz != 0u);
    if (t == 0) flag[0] = (b == 0ULL) ? 1 : 0;
}

__device__ inline unsigned short f2bf(float x) {
    unsigned int u = __float_as_uint(x);
    unsigned int r = (u + 0x7fffu + ((u >> 16) & 1u)) >> 16;  // RNE
    return (unsigned short)r;
}

// ---------------------------------------------------------------------------
// Node precompute as an LDS-tiled fp32 GEMM with register-prefetch dbuf.
//   C[n][j] = sum_k tok[n][k] * B[k][j],   j<128: B=w1[k][j] (P cols)
//                                          j>=128: B=w1[128+k][j-128] (Q cols)
// Epilogue adds the coord term (-cc for P, +cc+b1 for Q) and stores bf16.
// Block: 256 thr, 64 nodes x 256 cols; per-thread 8 nodes x (4 P + 4 Q cols).
// Per tile: ds_write staged regs -> issue next tile's global loads -> barrier
// -> compute (loads overlap FMAs) -> barrier.
// ---------------------------------------------------------------------------
__global__ __launch_bounds__(256) void node_pre3(
    const float* __restrict__ tokens, const float* __restrict__ coords,
    const float* __restrict__ w1, const float* __restrict__ b1,
    unsigned short* __restrict__ Pb, unsigned short* __restrict__ Qb, int N) {
    __shared__ float Bt[BK][NCOL];      // 16 KB
    __shared__ float Tt[BK][MBLK + 4];  // padded stride 68

    const int t  = threadIdx.x;
    const int n0 = blockIdx.x * MBLK;
    const int r0 = (t >> 5) * 8;   // node sub-block 0..56
    const int c0 = (t & 31) * 4;   // column group within 128

    const int sn = t >> 2;        // staging: node 0..63
    const int sk = (t & 3) * 4;   // staging: k sub-offset 0,4,8,12
    const int snode = n0 + sn;
    const bool svalid = snode < N;

    // staging-element coordinates for the 4 B-tile pieces this thread loads
    int brow[4], bcol[4];
    const float* bsrc[4];
#pragma unroll
    for (int p = 0; p < 4; ++p) {
        const int f     = t + p * 256;   // 0..1023
        const int chunk = f >> 9;        // 0: P cols (w1 rows 0..127), 1: Q cols
        const int fi    = f & 511;
        brow[p] = fi >> 5;               // 0..15 within tile
        bcol[p] = chunk * CH + (fi & 31) * 4;
        bsrc[p] = &w1[(size_t)(chunk * CH + brow[p]) * CH + (fi & 31) * 4];
    }

    float4 bstage[4];
    float4 tstage;

    // prologue: stage tile 0 into registers
#pragma unroll
    for (int p = 0; p < 4; ++p) bstage[p] = *(const float4*)bsrc[p];
    tstage = make_float4(0.f, 0.f, 0.f, 0.f);
    if (svalid) tstage = *(const float4*)&tokens[(size_t)snode * CH + sk];

    float acc[8][8];
#pragma unroll
    for (int i = 0; i < 8; ++i)
#pragma unroll
        for (int j = 0; j < 8; ++j) acc[i][j] = 0.f;

    for (int k0 = 0; k0 < CH; k0 += BK) {
        // write staged regs to LDS
#pragma unroll
        for (int p = 0; p < 4; ++p)
            *(float4*)&Bt[brow[p]][bcol[p]] = bstage[p];
        Tt[sk + 0][sn] = tstage.x;
        Tt[sk + 1][sn] = tstage.y;
        Tt[sk + 2][sn] = tstage.z;
        Tt[sk + 3][sn] = tstage.w;

        // prefetch next tile into registers (overlaps compute below)
        if (k0 + BK < CH) {
#pragma unroll
            for (int p = 0; p < 4; ++p)
                bstage[p] = *(const float4*)(bsrc[p] + (size_t)(k0 + BK) * CH);
            if (svalid)
                tstage = *(const float4*)&tokens[(size_t)snode * CH + k0 + BK + sk];
        }
        __syncthreads();

        // compute
#pragma unroll
        for (int k = 0; k < BK; ++k) {
            float a[8], b[8];
            *(float4*)&a[0] = *(const float4*)&Tt[k][r0];
            *(float4*)&a[4] = *(const float4*)&Tt[k][r0 + 4];
            *(float4*)&b[0] = *(const float4*)&Bt[k][c0];
            *(float4*)&b[4] = *(const float4*)&Bt[k][CH + c0];
#pragma unroll
            for (int i = 0; i < 8; ++i)
#pragma unroll
                for (int j = 0; j < 8; ++j)
                    acc[i][j] = fmaf(a[i], b[j], acc[i][j]);
        }
        __syncthreads();  // protect LDS before next tile's writes
    }

    // --- epilogue: coord terms + bias, convert to bf16, store ---
    const float4 wc0 = *(const float4*)&w1[(size_t)(2 * CH) * CH + c0];      // row 256
    const float4 wc1 = *(const float4*)&w1[(size_t)(2 * CH + 1) * CH + c0];  // row 257
    const float4 bb  = *(const float4*)&b1[c0];

#pragma unroll
    for (int i = 0; i < 8; ++i) {
        const int n = n0 + r0 + i;
        if (n < N) {
            const float cx = coords[2 * n];
            const float cy = coords[2 * n + 1];
            float cc[4];
            cc[0] = fmaf(cy, wc1.x, cx * wc0.x);
            cc[1] = fmaf(cy, wc1.y, cx * wc0.y);
            cc[2] = fmaf(cy, wc1.z, cx * wc0.z);
            cc[3] = fmaf(cy, wc1.w, cx * wc0.w);
            ushort4 ps, qs;
            ps.x = f2bf(acc[i][0] - cc[0]);
            ps.y = f2bf(acc[i][1] - cc[1]);
            ps.z = f2bf(acc[i][2] - cc[2]);
            ps.w = f2bf(acc[i][3] - cc[3]);
            qs.x = f2bf(acc[i][4] + cc[0] + bb.x);
            qs.y = f2bf(acc[i][5] + cc[1] + bb.y);
            qs.z = f2bf(acc[i][6] + cc[2] + bb.z);
            qs.w = f2bf(acc[i][7] + cc[3] + bb.w);
            *(ushort4*)&Pb[(size_t)n * CH + c0] = ps;
            *(ushort4*)&Qb[(size_t)n * CH + c0] = qs;
        }
    }
}

// ---------------------------------------------------------------------------
// Edge kernel: each 32-lane half-wave owns FOUR edges per iteration.
//   out[e] = dot(relu(P[src] + Q[dst]), w2) + b2
// 8 row-gathers issued back-to-back (8 outstanding VMEM/lane), then a shared
// 9-shfl butterfly reduces all four dot-products; lanes 0..3 store (16B).
// ---------------------------------------------------------------------------
__global__ __launch_bounds__(256) void edge_kernel3(
    const unsigned int* __restrict__ idxw, const unsigned short* __restrict__ Pb,
    const unsigned short* __restrict__ Qb, const float* __restrict__ w2,
    const float* __restrict__ b2, float* __restrict__ out, long long E,
    const int* __restrict__ flag) {
    const int is64 = flag[0];  // uniform
    const int t = threadIdx.x;
    const int l = t & 31;
    const long long nq   = (E + 3) >> 2;  // edge quads
    const long long hw0  = (long long)blockIdx.x * (blockDim.x >> 5) + (t >> 5);
    const long long nhws = (long long)gridDim.x * (blockDim.x >> 5);
    const float4 w2v = *(const float4*)&w2[4 * l];
    const float bias = b2[0];

    for (long long q = hw0; q < nq; q += nhws) {
        const long long e0 = q << 2;
        long long s[4], d[4];
#pragma unroll
        for (int i = 0; i < 4; ++i) {
            const long long e = e0 + i;
            const long long ec = (e < E) ? e : (E - 1);
            if (is64) {
                s[i] = (long long)idxw[2 * ec];
                d[i] = (long long)idxw[2 * (E + ec)];
            } else {
                s[i] = (long long)idxw[ec];
                d[i] = (long long)idxw[E + ec];
            }
        }
        uint2 pv[4], qv[4];
#pragma unroll
        for (int i = 0; i < 4; ++i)
            pv[i] = *(const uint2*)&Pb[s[i] * CH + 4 * l];
#pragma unroll
        for (int i = 0; i < 4; ++i)
            qv[i] = *(const uint2*)&Qb[d[i] * CH + 4 * l];

        float part[4];
#pragma unroll
        for (int i = 0; i < 4; ++i) {
            const float p0 = __uint_as_float(pv[i].x << 16);
            const float p1 = __uint_as_float(pv[i].x & 0xffff0000u);
            const float p2 = __uint_as_float(pv[i].y << 16);
            const float p3 = __uint_as_float(pv[i].y & 0xffff0000u);
            const float q0 = __uint_as_float(qv[i].x << 16);
            const float q1 = __uint_as_float(qv[i].x & 0xffff0000u);
            const float q2 = __uint_as_float(qv[i].y << 16);
            const float q3 = __uint_as_float(qv[i].y & 0xffff0000u);
            const float h0 = fmaxf(p0 + q0, 0.f);
            const float h1 = fmaxf(p1 + q1, 0.f);
            const float h2 = fmaxf(p2 + q2, 0.f);
            const float h3 = fmaxf(p3 + q3, 0.f);
            part[i] = h0 * w2v.x + h1 * w2v.y + h2 * w2v.z + h3 * w2v.w;
        }

        // shared butterfly: level 1 per edge, then pack by lane parity bits.
        // xor masks >= 2 preserve bit0; masks >= 4 preserve bits 0..1, so
        // packed classes stay separate. Lane L ends with edge (L&3)'s sum.
        float t0 = part[0] + __shfl_xor(part[0], 1);
        float t1 = part[1] + __shfl_xor(part[1], 1);
        float t2 = part[2] + __shfl_xor(part[2], 1);
        float t3 = part[3] + __shfl_xor(part[3], 1);
        float a = (l & 1) ? t1 : t0;
        float b = (l & 1) ? t3 : t2;
        a += __shfl_xor(a, 2);
        b += __shfl_xor(b, 2);
        float c = (l & 2) ? b : a;
        c += __shfl_xor(c, 4);
        c += __shfl_xor(c, 8);
        c += __shfl_xor(c, 16);

        if (l < 4 && e0 + l < E) out[e0 + l] = c + bias;
    }
}

extern "C" void kernel_launch(void* const* d_in, const int* in_sizes, int n_in,
                              void* d_out, int out_size, void* d_ws,
                              size_t ws_size, hipStream_t stream) {
    const float* tokens = (const float*)d_in[0];
    const float* coords = (const float*)d_in[1];
    const unsigned int* idxw = (const unsigned int*)d_in[2];  // int32 or int64 words
    const float* w1 = (const float*)d_in[3];
    const float* b1 = (const float*)d_in[4];
    const float* w2 = (const float*)d_in[5];
    const float* b2 = (const float*)d_in[6];
    float* out = (float*)d_out;

    const int N = in_sizes[0] / CH;       // 50000
    const long long E = in_sizes[2] / 2;  // 800000

    unsigned short* Pb = (unsigned short*)d_ws;
    unsigned short* Qb = Pb + (size_t)N * CH;
    int* flag = (int*)(Qb + (size_t)N * CH);

    detect_idx64<<<1, 64, 0, stream>>>(idxw, flag);

    const int nblk_node = (N + MBLK - 1) / MBLK;
    node_pre3<<<nblk_node, 256, 0, stream>>>(tokens, coords, w1, b1, Pb, Qb, N);

    edge_kernel3<<<4096, 256, 0, stream>>>(idxw, Pb, Qb, w2, b2, out, E, flag);
}

// Round 4
// 89.514 us; speedup vs baseline: 3.3762x; 1.4067x over previous
//
#include <hip/hip_runtime.h>

static constexpr int CH = 128;   // CHANNELS

typedef __attribute__((ext_vector_type(8))) short bf16x8;
typedef __attribute__((ext_vector_type(4))) float f32x4;

__device__ inline unsigned short f2bf(float x) {
    unsigned int u = __float_as_uint(x);
    unsigned int r = (u + 0x7fffu + ((u >> 16) & 1u)) >> 16;  // RNE
    return (unsigned short)r;
}

// ---------------------------------------------------------------------------
// Detect whether edge_index arrived as int64 (JAX x64 on) or int32 (x64 off).
// ---------------------------------------------------------------------------
__global__ void detect_idx64(const unsigned int* __restrict__ idxw,
                             int* __restrict__ flag) {
    const int t = threadIdx.x;
    unsigned int nz = 0;
    for (int i = t; i < 128; i += 64) nz |= idxw[2 * i + 1];
    unsigned long long b = __ballot(nz != 0u);
    if (t == 0) flag[0] = (b == 0ULL) ? 1 : 0;
}

// ---------------------------------------------------------------------------
// w1 (fp32 [258][128]) -> W (bf16 [256][128]), W[c][k] = B[k][c]:
//   c<128: B[k][c] = w1[k][c]   (P columns)
//   c>=128: B[k][c] = w1[128+k][c-128]  (Q columns)
// Coalesced float4 reads; scattered 2B writes (64 KB total, L2 absorbs).
// ---------------------------------------------------------------------------
__global__ __launch_bounds__(256) void w1_to_bfT(const float* __restrict__ w1,
                                                 unsigned short* __restrict__ W) {
    const int idx = blockIdx.x * 256 + threadIdx.x;  // 0..8191
    const int row = idx >> 5;                        // w1 row 0..255
    const int cq  = idx & 31;                        // col quad
    const float4 v = *(const float4*)&w1[(size_t)row * CH + cq * 4];
    const int half  = row >> 7;          // 0: P cols, 1: Q cols
    const int k     = row & 127;
    const int cbase = half * CH + cq * 4;
    W[(size_t)(cbase + 0) * CH + k] = f2bf(v.x);
    W[(size_t)(cbase + 1) * CH + k] = f2bf(v.y);
    W[(size_t)(cbase + 2) * CH + k] = f2bf(v.z);
    W[(size_t)(cbase + 3) * CH + k] = f2bf(v.w);
}

// ---------------------------------------------------------------------------
// Node stage as bf16 MFMA GEMM: per block 64 nodes x 256 cols, K=128.
// 4 waves, wave w owns cols w*64..w*64+63 (waves 0,1 = P; 2,3 = Q).
// A tile (tokens->bf16) in LDS, XOR-swizzled (G4). B frags hoisted to regs
// from W (global, L1-hot). Epilogue adds coord terms, transposes through a
// swizzled LDS out-tile, stores 16B-coalesced bf16 rows to Pb/Qb.
// ---------------------------------------------------------------------------
__global__ __launch_bounds__(256) void node_mfma(
    const float* __restrict__ tokens, const float* __restrict__ coords,
    const float* __restrict__ w1, const float* __restrict__ b1,
    const unsigned short* __restrict__ W, unsigned short* __restrict__ Pb,
    unsigned short* __restrict__ Qb, int N) {
    __shared__ unsigned short Atile[64 * 128];  // 16 KB, swizzled
    __shared__ unsigned short Otile[64 * 256];  // 32 KB, swizzled

    const int t    = threadIdx.x;
    const int l    = t & 63;
    const int wid  = t >> 6;
    const int n0   = blockIdx.x * 64;
    const int woff = wid * 64;
    const int bl   = l & 15;   // fragment row/col lane index
    const int bh   = l >> 4;   // fragment k-group / row-group

    // ---- B fragments: bfrag[ks][n] = B[ks*32 + bh*8 .. +8][woff + n*16 + bl]
    bf16x8 bfrag[4][4];
#pragma unroll
    for (int ks = 0; ks < 4; ++ks)
#pragma unroll
        for (int n = 0; n < 4; ++n)
            bfrag[ks][n] = *(const bf16x8*)&W[(size_t)(woff + n * 16 + bl) * CH +
                                              ks * 32 + bh * 8];

    // ---- stage A: tokens (fp32) -> bf16 LDS, swizzle byte ^= (row&7)<<4 ----
#pragma unroll
    for (int it = 0; it < 8; ++it) {
        const int idx  = it * 256 + t;   // 0..2047 float4s
        const int node = idx >> 5;
        const int kq   = idx & 31;
        float4 v = make_float4(0.f, 0.f, 0.f, 0.f);
        if (n0 + node < N)
            v = *(const float4*)&tokens[(size_t)(n0 + node) * CH + kq * 4];
        const unsigned int u0 = ((unsigned)f2bf(v.y) << 16) | f2bf(v.x);
        const unsigned int u1 = ((unsigned)f2bf(v.w) << 16) | f2bf(v.z);
        const int byte = node * 256 + ((kq * 8) ^ ((node & 7) << 4));
        *(uint2*)((char*)Atile + byte) = make_uint2(u0, u1);
    }
    __syncthreads();

    // ---- MFMA main: acc[m][n] over 4 K-steps ----
    f32x4 acc[4][4];
#pragma unroll
    for (int m = 0; m < 4; ++m)
#pragma unroll
        for (int n = 0; n < 4; ++n) acc[m][n] = (f32x4){0.f, 0.f, 0.f, 0.f};

#pragma unroll
    for (int ks = 0; ks < 4; ++ks) {
        bf16x8 afrag[4];
#pragma unroll
        for (int m = 0; m < 4; ++m) {
            const int row  = m * 16 + bl;
            const int byte = row * 256 + ((ks * 64 + bh * 16) ^ ((row & 7) << 4));
            afrag[m] = *(const bf16x8*)((const char*)Atile + byte);
        }
#pragma unroll
        for (int m = 0; m < 4; ++m)
#pragma unroll
            for (int n = 0; n < 4; ++n)
                acc[m][n] = __builtin_amdgcn_mfma_f32_16x16x32_bf16(
                    afrag[m], bfrag[ks][n], acc[m][n], 0, 0, 0);
    }

    // ---- epilogue: coord terms, bf16, swizzled LDS out-tile ----
    const int isQ = wid >= 2;
    float wc0v[4], wc1v[4], b1v[4];
#pragma unroll
    for (int n = 0; n < 4; ++n) {
        const int c = (wid & 1) * 64 + n * 16 + bl;  // col & 127
        wc0v[n] = w1[(size_t)(2 * CH) * CH + c];      // row 256
        wc1v[n] = w1[(size_t)(2 * CH + 1) * CH + c];  // row 257
        b1v[n]  = b1[c];
    }
#pragma unroll
    for (int m = 0; m < 4; ++m) {
#pragma unroll
        for (int r = 0; r < 4; ++r) {
            const int node = m * 16 + bh * 4 + r;  // local row (C/D layout, m89)
            const int gn = n0 + node;
            float cx = 0.f, cy = 0.f;
            if (gn < N) { cx = coords[2 * gn]; cy = coords[2 * gn + 1]; }
#pragma unroll
            for (int n = 0; n < 4; ++n) {
                const float v  = acc[m][n][r];
                const float cc = fmaf(cy, wc1v[n], cx * wc0v[n]);
                const float o  = isQ ? (v + cc + b1v[n]) : (v - cc);
                const int col  = woff + n * 16 + bl;
                const int byte = node * 512 + ((col * 2) ^ ((node & 7) << 4));
                *(unsigned short*)((char*)Otile + byte) = f2bf(o);
            }
        }
    }
    __syncthreads();

    // ---- coalesced store: 16B chunks, cols 0-127 -> Pb, 128-255 -> Qb ----
#pragma unroll
    for (int it = 0; it < 8; ++it) {
        const int idx  = it * 256 + t;  // 0..2047 chunks of 8 bf16
        const int node = idx >> 5;
        const int cg   = idx & 31;
        const int byte = node * 512 + ((cg * 16) ^ ((node & 7) << 4));
        const uint4 val = *(const uint4*)((const char*)Otile + byte);
        const int gn = n0 + node;
        if (gn < N) {
            if (cg < 16) *(uint4*)&Pb[(size_t)gn * CH + cg * 8] = val;
            else         *(uint4*)&Qb[(size_t)gn * CH + (cg - 16) * 8] = val;
        }
    }
}

// ---------------------------------------------------------------------------
// Edge kernel: each 32-lane half-wave owns EIGHT edges per iteration.
// 16 gathers issued back-to-back; 16-shfl shared butterfly; lanes 0..7 store
// 8 contiguous fp32 (32B coalesced).
// ---------------------------------------------------------------------------
__global__ __launch_bounds__(256) void edge_kernel8(
    const unsigned int* __restrict__ idxw, const unsigned short* __restrict__ Pb,
    const unsigned short* __restrict__ Qb, const float* __restrict__ w2,
    const float* __restrict__ b2, float* __restrict__ out, long long E,
    const int* __restrict__ flag) {
    const int is64 = flag[0];  // uniform
    const int t = threadIdx.x;
    const int l = t & 31;
    const long long no   = (E + 7) >> 3;  // edge octets
    const long long hw0  = (long long)blockIdx.x * (blockDim.x >> 5) + (t >> 5);
    const long long nhws = (long long)gridDim.x * (blockDim.x >> 5);
    const float4 w2v = *(const float4*)&w2[4 * l];
    const float bias = b2[0];

    for (long long q = hw0; q < no; q += nhws) {
        const long long e0 = q << 3;
        unsigned int s[8], d[8];
#pragma unroll
        for (int i = 0; i < 8; ++i) {
            const long long e = e0 + i;
            const long long ec = (e < E) ? e : (E - 1);
            if (is64) {
                s[i] = idxw[2 * ec];
                d[i] = idxw[2 * (E + ec)];
            } else {
                s[i] = idxw[ec];
                d[i] = idxw[E + ec];
            }
        }
        uint2 pv[8], qv[8];
#pragma unroll
        for (int i = 0; i < 8; ++i)
            pv[i] = *(const uint2*)&Pb[(size_t)s[i] * CH + 4 * l];
#pragma unroll
        for (int i = 0; i < 8; ++i)
            qv[i] = *(const uint2*)&Qb[(size_t)d[i] * CH + 4 * l];

        float part[8];
#pragma unroll
        for (int i = 0; i < 8; ++i) {
            const float p0 = __uint_as_float(pv[i].x << 16);
            const float p1 = __uint_as_float(pv[i].x & 0xffff0000u);
            const float p2 = __uint_as_float(pv[i].y << 16);
            const float p3 = __uint_as_float(pv[i].y & 0xffff0000u);
            const float q0 = __uint_as_float(qv[i].x << 16);
            const float q1 = __uint_as_float(qv[i].x & 0xffff0000u);
            const float q2 = __uint_as_float(qv[i].y << 16);
            const float q3 = __uint_as_float(qv[i].y & 0xffff0000u);
            const float h0 = fmaxf(p0 + q0, 0.f);
            const float h1 = fmaxf(p1 + q1, 0.f);
            const float h2 = fmaxf(p2 + q2, 0.f);
            const float h3 = fmaxf(p3 + q3, 0.f);
            part[i] = h0 * w2v.x + h1 * w2v.y + h2 * w2v.z + h3 * w2v.w;
        }

        // level 1 + pack by bit0
        float t0 = part[0] + __shfl_xor(part[0], 1);
        float t1 = part[1] + __shfl_xor(part[1], 1);
        float t2 = part[2] + __shfl_xor(part[2], 1);
        float t3 = part[3] + __shfl_xor(part[3], 1);
        float t4 = part[4] + __shfl_xor(part[4], 1);
        float t5 = part[5] + __shfl_xor(part[5], 1);
        float t6 = part[6] + __shfl_xor(part[6], 1);
        float t7 = part[7] + __shfl_xor(part[7], 1);
        float a0 = (l & 1) ? t1 : t0;
        float a1 = (l & 1) ? t3 : t2;
        float a2 = (l & 1) ? t5 : t4;
        float a3 = (l & 1) ? t7 : t6;
        // level 2 + pack by bit1
        a0 += __shfl_xor(a0, 2);
        a1 += __shfl_xor(a1, 2);
        a2 += __shfl_xor(a2, 2);
        a3 += __shfl_xor(a3, 2);
        float b0 = (l & 2) ? a1 : a0;
        float b1r = (l & 2) ? a3 : a2;
        // level 4 + pack by bit2
        b0  += __shfl_xor(b0, 4);
        b1r += __shfl_xor(b1r, 4);
        float c = (l & 4) ? b1r : b0;
        c += __shfl_xor(c, 8);
        c += __shfl_xor(c, 16);

        if (l < 8 && e0 + l < E) out[e0 + l] = c + bias;  // lane l holds edge l&7
    }
}

extern "C" void kernel_launch(void* const* d_in, const int* in_sizes, int n_in,
                              void* d_out, int out_size, void* d_ws,
                              size_t ws_size, hipStream_t stream) {
    const float* tokens = (const float*)d_in[0];
    const float* coords = (const float*)d_in[1];
    const unsigned int* idxw = (const unsigned int*)d_in[2];
    const float* w1 = (const float*)d_in[3];
    const float* b1 = (const float*)d_in[4];
    const float* w2 = (const float*)d_in[5];
    const float* b2 = (const float*)d_in[6];
    float* out = (float*)d_out;

    const int N = in_sizes[0] / CH;       // 50000
    const long long E = in_sizes[2] / 2;  // 800000

    unsigned short* Pb = (unsigned short*)d_ws;
    unsigned short* Qb = Pb + (size_t)N * CH;
    unsigned short* W  = Qb + (size_t)N * CH;          // 256*128 bf16
    int* flag = (int*)(W + 256 * CH);

    detect_idx64<<<1, 64, 0, stream>>>(idxw, flag);
    w1_to_bfT<<<32, 256, 0, stream>>>(w1, W);

    const int nblk_node = (N + 63) / 64;
    node_mfma<<<nblk_node, 256, 0, stream>>>(tokens, coords, w1, b1, W, Pb, Qb, N);

    edge_kernel8<<<4096, 256, 0, stream>>>(idxw, Pb, Qb, w2, b2, out, E, flag);
}

// Round 5
// 86.765 us; speedup vs baseline: 3.4832x; 1.0317x over previous
//
#include <hip/hip_runtime.h>

static constexpr int CH   = 128;   // CHANNELS
static constexpr int KW   = 160;   // W row length (bf16): 128 tok + wc0,wc1,b1 + pad
static constexpr int KPAD = 192;   // Atile row length (bf16) -> 384B rows (3x128B blocks)

typedef __attribute__((ext_vector_type(8))) short bf16x8;
typedef __attribute__((ext_vector_type(4))) float f32x4;

__device__ inline unsigned short f2bf(float x) {
    unsigned int u = __float_as_uint(x);
    unsigned int r = (u + 0x7fffu + ((u >> 16) & 1u)) >> 16;  // RNE
    return (unsigned short)r;
}
__device__ inline unsigned int pack2bf(float a, float b) {
    return (unsigned int)f2bf(a) | ((unsigned int)f2bf(b) << 16);
}

// ---------------------------------------------------------------------------
// Detect whether edge_index arrived as int64 (JAX x64 on) or int32 (x64 off).
// ---------------------------------------------------------------------------
__global__ void detect_idx64(const unsigned int* __restrict__ idxw,
                             int* __restrict__ flag) {
    const int t = threadIdx.x;
    unsigned int nz = 0;
    for (int i = t; i < 128; i += 64) nz |= idxw[2 * i + 1];
    unsigned long long b = __ballot(nz != 0u);
    if (t == 0) flag[0] = (b == 0ULL) ? 1 : 0;
}

// ---------------------------------------------------------------------------
// idx2[e] = { src_byte_off, dst_byte_off } (row = 256B). Pads to Epad with 0.
// ---------------------------------------------------------------------------
__global__ __launch_bounds__(256) void idx_prep(
    const unsigned int* __restrict__ idxw, uint2* __restrict__ idx2,
    long long E, long long Epad, const int* __restrict__ flag) {
    const int is64 = flag[0];
    const long long stride = (long long)gridDim.x * blockDim.x;
    for (long long i = (long long)blockIdx.x * blockDim.x + threadIdx.x;
         i < Epad; i += stride) {
        uint2 v = make_uint2(0u, 0u);
        if (i < E) {
            const unsigned s = is64 ? idxw[2 * i] : idxw[i];
            const unsigned d = is64 ? idxw[2 * (E + i)] : idxw[E + i];
            v = make_uint2(s << 8, d << 8);
        }
        idx2[i] = v;
    }
}

// ---------------------------------------------------------------------------
// W[c][k] (bf16, [256][KW]):
//   k<128 : B[k][c]  (c<128: w1[k][c] P-cols; c>=128: w1[128+k][c-128] Q-cols)
//   k=128 : -+wc0[c]  (sign -: P, +: Q)     k=129 : -+wc1[c]
//   k=130 : b1 (Q only)                     k>130 : 0
// ---------------------------------------------------------------------------
__global__ __launch_bounds__(192) void w1_prep(const float* __restrict__ w1,
                                               const float* __restrict__ b1,
                                               unsigned short* __restrict__ W) {
    const int c = blockIdx.x;    // 0..255
    const int k = threadIdx.x;
    if (k >= KW) return;
    const bool isQ = c >= 128;
    const int cc = c & 127;
    float v;
    if (k < 128)       v = isQ ? w1[(size_t)(128 + k) * CH + cc]
                               : w1[(size_t)k * CH + cc];
    else if (k == 128) v = (isQ ? 1.f : -1.f) * w1[(size_t)(2 * CH) * CH + cc];
    else if (k == 129) v = (isQ ? 1.f : -1.f) * w1[(size_t)(2 * CH + 1) * CH + cc];
    else if (k == 130) v = isQ ? b1[cc] : 0.f;
    else               v = 0.f;
    W[(size_t)c * KW + k] = f2bf(v);
}

// ---------------------------------------------------------------------------
// Node stage: 64 nodes x 256 cols, K=160 (coords+bias folded into GEMM).
// Swapped operands: A = W rows (cols of output), B = token frags ->
// D rows = output cols, so 4 acc regs = 4 consecutive cols => 8B packed
// global stores, no output LDS tile, no scalar epilogue.
// ---------------------------------------------------------------------------
__global__ __launch_bounds__(256) void node_mfma2(
    const float* __restrict__ tokens, const float* __restrict__ coords,
    const unsigned short* __restrict__ W, unsigned short* __restrict__ Pb,
    unsigned short* __restrict__ Qb, int N) {
    __shared__ unsigned short Atile[64 * KPAD];  // 24 KB, XOR-swizzled rows

    const int t    = threadIdx.x;
    const int l    = t & 63;
    const int wid  = t >> 6;
    const int n0   = blockIdx.x * 64;
    const int woff = wid * 64;
    const int bl   = l & 15;
    const int bh   = l >> 4;

    // ---- stage token chunks: rows [node][k0..127] as 16 x 16B chunks ----
#pragma unroll
    for (int it = 0; it < 4; ++it) {
        const int idx  = it * 256 + t;   // 0..1023
        const int node = idx >> 4;
        const int cq   = idx & 15;       // 16B chunk = 8 bf16 = k 8cq..8cq+7
        float4 v0 = make_float4(0.f, 0.f, 0.f, 0.f);
        float4 v1 = v0;
        if (n0 + node < N) {
            const float* src = &tokens[(size_t)(n0 + node) * CH + cq * 8];
            v0 = *(const float4*)src;
            v1 = *(const float4*)(src + 4);
        }
        uint4 u;
        u.x = pack2bf(v0.x, v0.y);
        u.y = pack2bf(v0.z, v0.w);
        u.z = pack2bf(v1.x, v1.y);
        u.w = pack2bf(v1.z, v1.w);
        const int byte = node * 384 + ((cq * 16) ^ ((node & 7) << 4));
        *(uint4*)((char*)Atile + byte) = u;
    }
    // ---- stage ext chunks: k=128..191 -> (cx, cy, 1, 0, ...) ----
#pragma unroll
    for (int it = 0; it < 2; ++it) {
        const int idx  = it * 256 + t;   // 0..511
        const int node = idx >> 3;
        const int ce   = idx & 7;        // chunk 16+ce
        uint4 u = make_uint4(0u, 0u, 0u, 0u);
        if (ce == 0 && n0 + node < N) {
            const float cx = coords[2 * (n0 + node)];
            const float cy = coords[2 * (n0 + node) + 1];
            u.x = pack2bf(cx, cy);
            u.y = pack2bf(1.f, 0.f);
        }
        const int byte = node * 384 + (((16 + ce) * 16) ^ ((node & 7) << 4));
        *(uint4*)((char*)Atile + byte) = u;
    }
    __syncthreads();

    // ---- MFMA: acc[m][n], m = col-group, n = node-group ----
    f32x4 acc[4][4];
#pragma unroll
    for (int m = 0; m < 4; ++m)
#pragma unroll
        for (int n = 0; n < 4; ++n) acc[m][n] = (f32x4){0.f, 0.f, 0.f, 0.f};

#pragma unroll
    for (int ks = 0; ks < 5; ++ks) {
        bf16x8 wfrag[4], tfrag[4];
#pragma unroll
        for (int m = 0; m < 4; ++m)
            wfrag[m] = *(const bf16x8*)&W[(size_t)(woff + m * 16 + bl) * KW +
                                          ks * 32 + bh * 8];
#pragma unroll
        for (int n = 0; n < 4; ++n) {
            const int row  = n * 16 + bl;
            const int byte = row * 384 + ((ks * 64 + bh * 16) ^ ((row & 7) << 4));
            tfrag[n] = *(const bf16x8*)((const char*)Atile + byte);
        }
#pragma unroll
        for (int m = 0; m < 4; ++m)
#pragma unroll
            for (int n = 0; n < 4; ++n)
                acc[m][n] = __builtin_amdgcn_mfma_f32_16x16x32_bf16(
                    wfrag[m], tfrag[n], acc[m][n], 0, 0, 0);
    }

    // ---- store: D rows = cols c = woff + m*16 + bh*4 + r (4 regs = 8B) ----
#pragma unroll
    for (int m = 0; m < 4; ++m) {
        const int c = woff + m * 16 + bh * 4;
        unsigned short* dst = (c < CH) ? Pb : Qb;
        const int cc = c & (CH - 1);
#pragma unroll
        for (int n = 0; n < 4; ++n) {
            const int node = n0 + n * 16 + bl;
            if (node < N) {
                uint2 val;
                val.x = pack2bf(acc[m][n][0], acc[m][n][1]);
                val.y = pack2bf(acc[m][n][2], acc[m][n][3]);
                *(uint2*)&dst[(size_t)node * CH + cc] = val;
            }
        }
    }
}

// ---------------------------------------------------------------------------
// Edge kernel: 16-lane group owns 4 edges/iter; lane covers 8 channels (16B).
//   out[e] = dot(relu(P[src] + Q[dst]), w2) + b2
// ---------------------------------------------------------------------------
__global__ __launch_bounds__(256) void edge_g16(
    const uint2* __restrict__ idx2, const char* __restrict__ Pb,
    const char* __restrict__ Qb, const float* __restrict__ w2,
    const float* __restrict__ b2, float* __restrict__ out, long long E) {
    const int t  = threadIdx.x;
    const int l  = t & 63;
    const int g  = (l >> 4);   // group 0..3
    const int gl = l & 15;
    const long long nch = (E + 15) >> 4;                       // 16-edge chunks
    const long long w0  = (long long)blockIdx.x * 4 + (t >> 6);
    const long long nw  = (long long)gridDim.x * 4;
    const float4 w2a = *(const float4*)&w2[8 * gl];
    const float4 w2b = *(const float4*)&w2[8 * gl + 4];
    const float bias = b2[0];

    for (long long chk = w0; chk < nch; chk += nw) {
        const long long e0 = chk << 4;
        const uint4 i01 = *(const uint4*)&idx2[e0 + g * 4];      // edges j=0,1
        const uint4 i23 = *(const uint4*)&idx2[e0 + g * 4 + 2];  // edges j=2,3
        unsigned soff[4] = {i01.x, i01.z, i23.x, i23.z};
        unsigned doff[4] = {i01.y, i01.w, i23.y, i23.w};
        uint4 pv[4], qv[4];
#pragma unroll
        for (int j = 0; j < 4; ++j)
            pv[j] = *(const uint4*)(Pb + soff[j] + 16 * gl);
#pragma unroll
        for (int j = 0; j < 4; ++j)
            qv[j] = *(const uint4*)(Qb + doff[j] + 16 * gl);

        float part[4];
#pragma unroll
        for (int j = 0; j < 4; ++j) {
            float acc = 0.f;
            const unsigned pw[4] = {pv[j].x, pv[j].y, pv[j].z, pv[j].w};
            const unsigned qw[4] = {qv[j].x, qv[j].y, qv[j].z, qv[j].w};
            const float wv[8] = {w2a.x, w2a.y, w2a.z, w2a.w,
                                 w2b.x, w2b.y, w2b.z, w2b.w};
#pragma unroll
            for (int wdx = 0; wdx < 4; ++wdx) {
                const float plo = __uint_as_float(pw[wdx] << 16);
                const float phi = __uint_as_float(pw[wdx] & 0xffff0000u);
                const float qlo = __uint_as_float(qw[wdx] << 16);
                const float qhi = __uint_as_float(qw[wdx] & 0xffff0000u);
                const float hlo = fmaxf(plo + qlo, 0.f);
                const float hhi = fmaxf(phi + qhi, 0.f);
                acc = fmaf(hlo, wv[2 * wdx], acc);
                acc = fmaf(hhi, wv[2 * wdx + 1], acc);
            }
            part[j] = acc;
        }

        // width-16 butterfly with packing; lane (l&3)=j ends with edge j's sum
        float t0 = part[0] + __shfl_xor(part[0], 1);
        float t1 = part[1] + __shfl_xor(part[1], 1);
        float t2 = part[2] + __shfl_xor(part[2], 1);
        float t3 = part[3] + __shfl_xor(part[3], 1);
        float a0 = (l & 1) ? t1 : t0;
        float a1 = (l & 1) ? t3 : t2;
        a0 += __shfl_xor(a0, 2);
        a1 += __shfl_xor(a1, 2);
        float c = (l & 2) ? a1 : a0;
        c += __shfl_xor(c, 4);
        c += __shfl_xor(c, 8);

        const long long eo = e0 + g * 4 + (l & 3);
        if (gl < 4 && eo < E) out[eo] = c + bias;
    }
}

extern "C" void kernel_launch(void* const* d_in, const int* in_sizes, int n_in,
                              void* d_out, int out_size, void* d_ws,
                              size_t ws_size, hipStream_t stream) {
    const float* tokens = (const float*)d_in[0];
    const float* coords = (const float*)d_in[1];
    const unsigned int* idxw = (const unsigned int*)d_in[2];
    const float* w1 = (const float*)d_in[3];
    const float* b1 = (const float*)d_in[4];
    const float* w2 = (const float*)d_in[5];
    const float* b2 = (const float*)d_in[6];
    float* out = (float*)d_out;

    const int N = in_sizes[0] / CH;       // 50000
    const long long E = in_sizes[2] / 2;  // 800000
    const long long Epad = ((E + 15) >> 4) << 4;

    unsigned short* Pb = (unsigned short*)d_ws;
    unsigned short* Qb = Pb + (size_t)N * CH;
    uint2* idx2 = (uint2*)(Qb + (size_t)N * CH);
    unsigned short* W = (unsigned short*)(idx2 + Epad);
    int* flag = (int*)(W + 256 * KW);

    detect_idx64<<<1, 64, 0, stream>>>(idxw, flag);
    idx_prep<<<1024, 256, 0, stream>>>(idxw, idx2, E, Epad, flag);
    w1_prep<<<256, 192, 0, stream>>>(w1, b1, W);

    const int nblk_node = (N + 63) / 64;
    node_mfma2<<<nblk_node, 256, 0, stream>>>(tokens, coords, W, Pb, Qb, N);

    edge_g16<<<4096, 256, 0, stream>>>(idx2, (const char*)Pb, (const char*)Qb,
                                       w2, b2, out, E);
}